// Round 7
// baseline (349.055 us; speedup 1.0000x reference)
//
#include <hip/hip_runtime.h>
#include <math.h>

#define B    32
#define INF  784
#define H1   1024
#define H2   1024
#define NC   10
#define EPSV 0.1f

typedef __attribute__((ext_vector_type(8))) short short8;
typedef __attribute__((ext_vector_type(4))) float floatx4;

__device__ inline ushort bf16_rne(float f) {
  uint u = __builtin_bit_cast(uint, f);
  u += 0x7FFFu + ((u >> 16) & 1u);
  return (ushort)(u >> 16);
}
__device__ inline uint pack2(float a, float b) {
  return (uint)bf16_rne(a) | ((uint)bf16_rne(b) << 16);
}
// scale a packed pair of bf16 (in dword u) by d0,d1 and repack
__device__ inline uint scale_pack(uint u, float d0, float d1v) {
  float f0 = __builtin_bit_cast(float, u << 16) * d0;
  float f1 = __builtin_bit_cast(float, u & 0xFFFF0000u) * d1v;
  uint r0 = __builtin_bit_cast(uint, f0) + 0x8000u;
  uint r1 = __builtin_bit_cast(uint, f1) + 0x8000u;
  return __builtin_amdgcn_perm(r1, r0, 0x07060302u);
}

// ---------------------------------------------------------------------------
// K_PRE: merged preprocessing + zero-init.
//  [0,64):     W2F fragment pack
//  [64,113):   W1F fragment pack via LDS transpose (coalesced reads)
//  [113,1137): layer-1 row i = bid-113
//  [1137,1144): zero E/F/F2 region (54272 floats from E base)
// ---------------------------------------------------------------------------
__global__ __launch_bounds__(256) void k_pre(
    const float* __restrict__ x, const float* __restrict__ W1,
    const float* __restrict__ b1, const float* __restrict__ W2,
    ushort* __restrict__ W1F, ushort* __restrict__ W2F,
    float* __restrict__ d1B, float* __restrict__ t1B, float* __restrict__ dnB,
    float* __restrict__ Ezero)
{
  __shared__ float red[4][B + 1];
  __shared__ float Ts[4][32][17];
  int bid = blockIdx.x;
  int t = threadIdx.x;
  if (bid < 64) {
    int jt = bid;
    int lane = t & 63, c0 = t >> 6;
    int l15 = lane & 15, quad = lane >> 4;
    for (int c = c0; c < 32; c += 4) {
      const float* src = &W2[(size_t)(jt * 16 + l15) * H1 + c * 32 + quad * 8];
      float4 v0 = *reinterpret_cast<const float4*>(src);
      float4 v1 = *reinterpret_cast<const float4*>(src + 4);
      uint4 o;
      o.x = pack2(v0.x, v0.y); o.y = pack2(v0.z, v0.w);
      o.z = pack2(v1.x, v1.y); o.w = pack2(v1.z, v1.w);
      *reinterpret_cast<uint4*>(&W2F[((size_t)(c * 64 + jt) * 64 + lane) * 8]) = o;
    }
  } else if (bid < 113) {
    int mt = bid - 64;
    int col0 = mt * 16;
    int w = t >> 6, lane = t & 63;
    int l15 = lane & 15, quad = lane >> 4;
    for (int cg = 0; cg < 8; cg++) {
      int c = cg * 4 + w;
#pragma unroll
      for (int p = 0; p < 8; p++) {
        int r = p * 4 + (lane >> 4);
        Ts[w][r][lane & 15] = W1[(size_t)(c * 32 + r) * INF + col0 + (lane & 15)];
      }
      float f[8];
#pragma unroll
      for (int e = 0; e < 8; e++) f[e] = Ts[w][quad * 8 + e][l15];
      uint4 o;
      o.x = pack2(f[0], f[1]); o.y = pack2(f[2], f[3]);
      o.z = pack2(f[4], f[5]); o.w = pack2(f[6], f[7]);
      *reinterpret_cast<uint4*>(&W1F[((size_t)(c * 49 + mt) * 64 + lane) * 8]) = o;
    }
  } else if (bid < 1137) {
    int i = bid - 113;
    const float* w = W1 + (size_t)i * INF;
    float acc[B];
#pragma unroll
    for (int b = 0; b < B; b++) acc[b] = 0.f;
    float wabs = 0.f;
    for (int k = t; k < INF; k += 256) {
      float wv = w[k];
      wabs += fabsf(wv);
#pragma unroll
      for (int b = 0; b < B; b++) acc[b] = fmaf(x[b * INF + k], wv, acc[b]);
    }
#pragma unroll
    for (int off = 32; off > 0; off >>= 1) {
#pragma unroll
      for (int b = 0; b < B; b++) acc[b] += __shfl_down(acc[b], off, 64);
      wabs += __shfl_down(wabs, off, 64);
    }
    int wave = t >> 6, lane = t & 63;
    if (lane == 0) {
#pragma unroll
      for (int b = 0; b < B; b++) red[wave][b] = acc[b];
      red[wave][B] = wabs;
    }
    __syncthreads();
    if (t < B) {
      float s = red[0][t] + red[1][t] + red[2][t] + red[3][t];
      float r = EPSV * (red[0][B] + red[1][B] + red[2][B] + red[3][B]);
      float nom = s + b1[i];
      float zl = nom - r, zu = nom + r;
      float d, l;
      if (zl >= 0.f)      { d = 1.f;            l = 0.f; }
      else if (zu > 0.f)  { d = zu / (zu - zl); l = zl;  }
      else                { d = 0.f;            l = 0.f; }
      d1B[(size_t)t * H1 + i] = d;
      t1B[(size_t)t * H1 + i] = d * l;
      dnB[(size_t)t * H1 + i] = d * nom;
    }
  } else {
    int zb = bid - 1137;
    for (int idx = t; idx < 8192; idx += 256) {
      int pos = zb * 8192 + idx;
      if (pos < 54272) Ezero[pos] = 0.f;
    }
  }
}

// ---------------------------------------------------------------------------
// K_SCALEA: W1S[b] = W1F scaled by d1[b] (bf16, fragment order preserved)
// ---------------------------------------------------------------------------
__global__ __launch_bounds__(256) void k_scaleA(
    const ushort* __restrict__ W1F, const float* __restrict__ d1B,
    ushort* __restrict__ W1S)
{
  int u4 = blockIdx.x * 256 + threadIdx.x;  // 0..100351
  int b = blockIdx.y;
  int c = u4 / 3136;
  int lane = u4 & 63;
  int quad = lane >> 4;
  int i = c * 32 + quad * 8;
  uint4 v = reinterpret_cast<const uint4*>(W1F)[u4];
  float4 d0 = *reinterpret_cast<const float4*>(&d1B[(size_t)b * H1 + i]);
  float4 d1v = *reinterpret_cast<const float4*>(&d1B[(size_t)b * H1 + i + 4]);
  uint4 o;
  o.x = scale_pack(v.x, d0.x, d0.y);
  o.y = scale_pack(v.y, d0.z, d0.w);
  o.z = scale_pack(v.z, d1v.x, d1v.y);
  o.w = scale_pack(v.w, d1v.z, d1v.w);
  reinterpret_cast<uint4*>(W1S)[(size_t)b * 100352 + u4] = o;
}

// ---------------------------------------------------------------------------
// K3_S: E[j,b] = eps * sum_k | sum_i W1S[b][i,k] * W2[j,i] |
// Pure load->MFMA.  XCD-swizzled grid (224, 8): x = b*7 + mtgrp; since
// 224 % 8 == 0, linear_id % 8 == x % 8 -> all 8 jt-copies of one (b, mt-slice)
// land on the SAME XCD and share its L2 slab (A fetched from HBM once).
// ---------------------------------------------------------------------------
#define K3_LOAD(c, A, Bv) do {                                                  \
  _Pragma("unroll")                                                             \
  for (int ni = 0; ni < 2; ni++)                                                \
    Bv[ni] = *reinterpret_cast<const uint4*>(bBase + (size_t)(c) * 32768 + ni * 512); \
  _Pragma("unroll")                                                             \
  for (int mi = 0; mi < 7; mi++)                                                \
    A[mi] = *reinterpret_cast<const uint4*>(aBase + (size_t)(c) * 25088 + mi * 512); \
} while (0)

#define K3S_COMP(A, Bv) do {                                                    \
  _Pragma("unroll")                                                             \
  for (int mi = 0; mi < 7; mi++) {                                              \
    short8 af = __builtin_bit_cast(short8, A[mi]);                              \
    _Pragma("unroll")                                                           \
    for (int ni = 0; ni < 2; ni++)                                              \
      acc[mi][ni] = __builtin_amdgcn_mfma_f32_16x16x32_bf16(af,                 \
          __builtin_bit_cast(short8, Bv[ni]), acc[mi][ni], 0, 0, 0);            \
  }                                                                             \
} while (0)

__global__ __launch_bounds__(256, 4) void k3_s(
    const ushort* __restrict__ W1S, const ushort* __restrict__ W2F,
    float* __restrict__ E)
{
  int t = threadIdx.x, w = t >> 6, lane = t & 63;
  int l15 = lane & 15;
  int bm = blockIdx.x;          // 0..223
  int b = bm / 7;
  int mt0 = (bm - b * 7) * 7;
  int jt0 = blockIdx.y * 8 + w * 2;

  const ushort* aBase = W1S + (size_t)b * 802816 + ((size_t)mt0 * 64 + lane) * 8;
  const ushort* bBase = W2F + ((size_t)jt0 * 64 + lane) * 8;

  floatx4 acc[7][2];
#pragma unroll
  for (int mi = 0; mi < 7; mi++)
#pragma unroll
    for (int ni = 0; ni < 2; ni++) acc[mi][ni] = (floatx4){0.f, 0.f, 0.f, 0.f};

  uint4 a0[7], b0[2], a1[7], b1v[2];
  K3_LOAD(0, a0, b0);
  K3_LOAD(1, a1, b1v);
  for (int c = 0; c < 30; c += 2) {
    K3S_COMP(a0, b0);
    K3_LOAD(c + 2, a0, b0);
    K3S_COMP(a1, b1v);
    if (c + 3 < 32) K3_LOAD(c + 3, a1, b1v);
  }
  K3S_COMP(a0, b0);
  K3S_COMP(a1, b1v);

#pragma unroll
  for (int ni = 0; ni < 2; ni++) {
    float s = 0.f;
#pragma unroll
    for (int mi = 0; mi < 7; mi++)
#pragma unroll
      for (int r = 0; r < 4; r++) s += fabsf(acc[mi][ni][r]);
    s += __shfl_xor(s, 16, 64);
    s += __shfl_xor(s, 32, 64);
    if (lane < 16) {
      int j = (jt0 + ni) * 16 + l15;
      atomicAdd(&E[(size_t)j * B + b], EPSV * s);
    }
  }
}

// ---------------------------------------------------------------------------
// K3 fallback (in-loop scaling) for small ws_size.
// ---------------------------------------------------------------------------
#define K3F_COMP(c, A, Bv) do {                                                 \
  float4 dv0 = *reinterpret_cast<const float4*>(&Ds[(c) * 32 + quad * 8]);      \
  float4 dv1 = *reinterpret_cast<const float4*>(&Ds[(c) * 32 + quad * 8 + 4]);  \
  short8 bfr[2];                                                                \
  _Pragma("unroll")                                                             \
  for (int ni = 0; ni < 2; ni++) {                                              \
    uint4 sb;                                                                   \
    sb.x = scale_pack(Bv[ni].x, dv0.x, dv0.y);                                  \
    sb.y = scale_pack(Bv[ni].y, dv0.z, dv0.w);                                  \
    sb.z = scale_pack(Bv[ni].z, dv1.x, dv1.y);                                  \
    sb.w = scale_pack(Bv[ni].w, dv1.z, dv1.w);                                  \
    bfr[ni] = __builtin_bit_cast(short8, sb);                                   \
  }                                                                             \
  _Pragma("unroll")                                                             \
  for (int mi = 0; mi < 7; mi++) {                                              \
    short8 af = __builtin_bit_cast(short8, A[mi]);                              \
    _Pragma("unroll")                                                           \
    for (int ni = 0; ni < 2; ni++)                                              \
      acc[mi][ni] = __builtin_amdgcn_mfma_f32_16x16x32_bf16(af, bfr[ni], acc[mi][ni], 0, 0, 0); \
  }                                                                             \
} while (0)

__global__ __launch_bounds__(256, 2) void k3_fb(
    const ushort* __restrict__ W1F, const ushort* __restrict__ W2F,
    const float* __restrict__ d1B, float* __restrict__ E)
{
  int b = blockIdx.z;
  int t = threadIdx.x, w = t >> 6, lane = t & 63;
  int quad = lane >> 4, l15 = lane & 15;
  int mt0 = blockIdx.x * 7;
  int jt0 = blockIdx.y * 8 + w * 2;

  __shared__ float Ds[H1];
  for (int idx = t; idx < H1; idx += 256) Ds[idx] = d1B[(size_t)b * H1 + idx];
  __syncthreads();

  const ushort* aBase = W1F + ((size_t)mt0 * 64 + lane) * 8;
  const ushort* bBase = W2F + ((size_t)jt0 * 64 + lane) * 8;

  floatx4 acc[7][2];
#pragma unroll
  for (int mi = 0; mi < 7; mi++)
#pragma unroll
    for (int ni = 0; ni < 2; ni++) acc[mi][ni] = (floatx4){0.f, 0.f, 0.f, 0.f};

  uint4 a0[7], b0[2], a1[7], b1v[2];
  K3_LOAD(0, a0, b0);
  K3_LOAD(1, a1, b1v);
  for (int c = 0; c < 30; c += 2) {
    K3F_COMP(c, a0, b0);
    K3_LOAD(c + 2, a0, b0);
    K3F_COMP(c + 1, a1, b1v);
    if (c + 3 < 32) K3_LOAD(c + 3, a1, b1v);
  }
  K3F_COMP(30, a0, b0);
  K3F_COMP(31, a1, b1v);

#pragma unroll
  for (int ni = 0; ni < 2; ni++) {
    float s = 0.f;
#pragma unroll
    for (int mi = 0; mi < 7; mi++)
#pragma unroll
      for (int r = 0; r < 4; r++) s += fabsf(acc[mi][ni][r]);
    s += __shfl_xor(s, 16, 64);
    s += __shfl_xor(s, 32, 64);
    if (lane < 16) {
      int j = (jt0 + ni) * 16 + l15;
      atomicAdd(&E[(size_t)j * B + b], EPSV * s);
    }
  }
}

// ---------------------------------------------------------------------------
// K245A: fused k2 matvecs + combine + nu2 build.  One block per j (= i2).
//  phase1: A/Cl/Cu matvecs over i for all 32 b -> d2,t2,db2 (smem only)
//  phase2: nu2T[b][j][jc] = (W3[yb,j]-W3[jc,j])*d2[b]; F2 slot atomics.
//  NOTE: B*NC = 320 > 256 threads -> phase2 MUST be a strided loop (r6 bug).
// ---------------------------------------------------------------------------
__global__ __launch_bounds__(256) void k245a(
    const float* __restrict__ W2, const float* __restrict__ b2,
    const float* __restrict__ dnB, const float* __restrict__ t1B,
    const float* __restrict__ E, const float* __restrict__ W3,
    const int* __restrict__ y,
    float* __restrict__ nu2T, float* __restrict__ F2)
{
  int j = blockIdx.x;
  int t = threadIdx.x;
  int wave = t >> 6, lane = t & 63;
  int b0 = wave * 8;
  float aA[8] = {}, aCl[8] = {}, aCu[8] = {};
  const float* __restrict__ w2 = W2 + (size_t)j * H1;
  for (int i = lane; i < H1; i += 64) {
    float wv = w2[i];
    float wp = fmaxf(wv, 0.f), wn = fmaxf(-wv, 0.f);
#pragma unroll
    for (int r = 0; r < 8; r++) {
      float dv = dnB[(size_t)(b0 + r) * H1 + i];
      float tv = t1B[(size_t)(b0 + r) * H1 + i];
      aA[r]  = fmaf(wv, dv, aA[r]);
      aCl[r] = fmaf(wn, tv, aCl[r]);
      aCu[r] = fmaf(wp, tv, aCu[r]);
    }
  }
#pragma unroll
  for (int off = 32; off > 0; off >>= 1) {
#pragma unroll
    for (int r = 0; r < 8; r++) {
      aA[r]  += __shfl_down(aA[r],  off, 64);
      aCl[r] += __shfl_down(aCl[r], off, 64);
      aCu[r] += __shfl_down(aCu[r], off, 64);
    }
  }
  __shared__ float sA[B], sCl[B], sCu[B];
  __shared__ float sd2[B], st2[B], sdb[B], swy[B], sw3[NC];
  float bj = b2[j];
  if (lane == 0) {
#pragma unroll
    for (int r = 0; r < 8; r++) {
      sA [b0 + r] = aA[r] + bj;
      sCl[b0 + r] = aCl[r];
      sCu[b0 + r] = aCu[r];
    }
  }
  if (t >= 64 && t < 96)   swy[t - 64]  = W3[(size_t)y[t - 64] * H2 + j];
  if (t >= 128 && t < 138) sw3[t - 128] = W3[(size_t)(t - 128) * H2 + j];
  __syncthreads();
  if (t < B) {
    float a = sA[t], e = E[(size_t)j * B + t];
    float zl = a - e + sCl[t];
    float zu = a + e - sCu[t];
    float d, l;
    if (zl >= 0.f)      { d = 1.f;            l = 0.f; }
    else if (zu > 0.f)  { d = zu / (zu - zl); l = zl;  }
    else                { d = 0.f;            l = 0.f; }
    sd2[t] = d;
    st2[t] = d * l;
    sdb[t] = d * bj;
  }
  __syncthreads();
  for (int tt = t; tt < B * NC; tt += 256) {   // B*NC=320 > 256: strided!
    int b = tt / NC, jc = tt - b * NC;
    float cw = swy[b] - sw3[jc];
    float d2v = sd2[b];
    nu2T[((size_t)b * H2 + j) * 12 + jc] = cw * d2v;
    float val = cw * sdb[b] + fmaxf(-cw, 0.f) * st2[b];
    atomicAdd(&F2[((size_t)(j & 63) * B + b) * NC + jc], val);
  }
}

// ---------------------------------------------------------------------------
// K5b1: hpart[s][b][j][i1] = sum_{i2 in half s} nu2T[b][i2][j] * W2[i2,i1]
// ---------------------------------------------------------------------------
__global__ __launch_bounds__(128) void k5b1(
    const float* __restrict__ W2, const float* __restrict__ nu2T,
    float* __restrict__ hpart)
{
  int t = threadIdx.x;
  int i1 = blockIdx.x * 128 + t;
  int b = blockIdx.y, s = blockIdx.z;
  const float* __restrict__ nrowb = nu2T + ((size_t)b * H2 + s * 512) * 12;
  const float* __restrict__ w2b = W2 + (size_t)s * 512 * H1 + i1;
  float h[NC] = {};
  for (int i2 = 0; i2 < 512; i2++) {
    float w2v = w2b[(size_t)i2 * H1];
    const float* __restrict__ nrow = nrowb + i2 * 12;
#pragma unroll
    for (int j = 0; j < NC; j++) h[j] = fmaf(nrow[j], w2v, h[j]);
  }
#pragma unroll
  for (int j = 0; j < NC; j++)
    hpart[(((size_t)s * B + b) * NC + j) * H1 + i1] = h[j];
}

// ---------------------------------------------------------------------------
// K5b2: h = hpart0+hpart1; nu1fT[b][i1][j] = h*d1; F += h*dn + relu(-h)*t1m
// ---------------------------------------------------------------------------
__global__ __launch_bounds__(256) void k5b2(
    const float* __restrict__ hpart,
    const float* __restrict__ d1B, const float* __restrict__ t1B,
    const float* __restrict__ dnB,
    float* __restrict__ nu1fT, float* __restrict__ F)
{
  int t = threadIdx.x;
  int i1 = blockIdx.x * 256 + t;
  int b = blockIdx.y;
  float d1v = d1B[(size_t)b * H1 + i1];
  float t1v = t1B[(size_t)b * H1 + i1];
  float dnv = dnB[(size_t)b * H1 + i1];
  float sn[NC], c1[NC];
#pragma unroll
  for (int j = 0; j < NC; j++) {
    float hv = hpart[((size_t)b * NC + j) * H1 + i1]
             + hpart[(((size_t)B + b) * NC + j) * H1 + i1];
    nu1fT[((size_t)b * H1 + i1) * 12 + j] = hv * d1v;
    sn[j] = hv * dnv;
    c1[j] = fmaxf(-hv, 0.f) * t1v;
  }
#pragma unroll
  for (int off = 32; off > 0; off >>= 1) {
#pragma unroll
    for (int j = 0; j < NC; j++) {
      sn[j] += __shfl_down(sn[j], off, 64);
      c1[j] += __shfl_down(c1[j], off, 64);
    }
  }
  __shared__ float red[4][2 * NC];
  int wave = t >> 6, lane = t & 63;
  if (lane == 0) {
#pragma unroll
    for (int j = 0; j < NC; j++) { red[wave][j] = sn[j]; red[wave][NC + j] = c1[j]; }
  }
  __syncthreads();
  if (t < NC) {
    float s = 0.f;
    for (int w = 0; w < 4; w++) s += red[w][t] + red[w][NC + t];
    atomicAdd(&F[b * NC + t], s);
  }
}

// ---------------------------------------------------------------------------
// K5c1: ppart[s][b][j][k] = sum_{i1 in half s} nu1fT[b][i1][j] * W1[i1,k]
// ---------------------------------------------------------------------------
__global__ __launch_bounds__(128) void k5c1(
    const float* __restrict__ W1, const float* __restrict__ nu1fT,
    float* __restrict__ ppart)
{
  int t = threadIdx.x;
  bool valid = (t < 112);
  int k = blockIdx.x * 112 + (valid ? t : 0);
  int b = blockIdx.y, s = blockIdx.z;
  const float* __restrict__ nrowb = nu1fT + ((size_t)b * H1 + s * 512) * 12;
  const float* __restrict__ w1b = W1 + (size_t)s * 512 * INF + k;
  float acc[NC] = {};
  for (int i1 = 0; i1 < 512; i1++) {
    float w1v = w1b[(size_t)i1 * INF];
    const float* __restrict__ nrow = nrowb + i1 * 12;
#pragma unroll
    for (int j = 0; j < NC; j++) acc[j] = fmaf(nrow[j], w1v, acc[j]);
  }
  if (valid) {
#pragma unroll
    for (int j = 0; j < NC; j++)
      ppart[(((size_t)s * B + b) * NC + j) * INF + k] = acc[j];
  }
}

// ---------------------------------------------------------------------------
// K5c2 + out: per b: Ef[j] = eps*sum_k |p0+p1|;
// out = eps*Ef - (F + sum_slots F2 + b3[yb]-b3[jc]).
// ---------------------------------------------------------------------------
__global__ __launch_bounds__(256) void k5c2_out(
    const float* __restrict__ ppart, const float* __restrict__ F,
    const float* __restrict__ F2, const float* __restrict__ b3,
    const int* __restrict__ y, float* __restrict__ out)
{
  int b = blockIdx.x;
  int t = threadIdx.x;
  float e[NC] = {};
  for (int k = t; k < INF; k += 256) {
#pragma unroll
    for (int j = 0; j < NC; j++) {
      float v = ppart[((size_t)b * NC + j) * INF + k]
              + ppart[(((size_t)B + b) * NC + j) * INF + k];
      e[j] += fabsf(v);
    }
  }
#pragma unroll
  for (int off = 32; off > 0; off >>= 1) {
#pragma unroll
    for (int j = 0; j < NC; j++) e[j] += __shfl_down(e[j], off, 64);
  }
  __shared__ float red[4][NC];
  int wave = t >> 6, lane = t & 63;
  if (lane == 0) {
#pragma unroll
    for (int j = 0; j < NC; j++) red[wave][j] = e[j];
  }
  __syncthreads();
  if (t < NC) {
    float ef = 0.f;
    for (int w = 0; w < 4; w++) ef += red[w][t];
    float s = F[b * NC + t];
    for (int slot = 0; slot < 64; slot++)
      s += F2[((size_t)slot * B + b) * NC + t];
    int yb = y[b];
    s += b3[yb] - b3[t];
    out[b * NC + t] = EPSV * ef - s;
  }
}

// ---------------------------------------------------------------------------
extern "C" void kernel_launch(void* const* d_in, const int* in_sizes, int n_in,
                              void* d_out, int out_size, void* d_ws, size_t ws_size,
                              hipStream_t stream) {
  const float* x  = (const float*)d_in[0];
  const int*   y  = (const int*)  d_in[1];
  const float* W1 = (const float*)d_in[2];
  const float* b1 = (const float*)d_in[3];
  const float* W2 = (const float*)d_in[4];
  const float* b2 = (const float*)d_in[5];
  const float* W3 = (const float*)d_in[6];
  const float* b3 = (const float*)d_in[7];
  float* out = (float*)d_out;
  float* ws  = (float*)d_ws;

  // ---- workspace layout (floats), with lifetime overlays ----
  float* d1B  = ws;
  float* t1B  = ws + 32768;
  float* dnB  = ws + 65536;
  float* E    = ws + 196608;    // 32768 (zeroed in k_pre)
  float* F    = ws + 229376;    // 320, pad to 1024 (zeroed)
  float* F2   = ws + 230400;    // 64*32*10 = 20480 (zeroed; zero-range = 54272 from E)
  float* nu2T = ws + 328704;    // 393216, k245a -> k5b1 (ends 721920)
  ushort* W2F = (ushort*)(ws + 721920);    // 1048576 us (ends 1246208)
  ushort* W1F = (ushort*)(ws + 1246208);   // 802816 us (ends 1647616)
  ushort* W1S = (ushort*)(ws + 1647616);   // 32*802816 us = 51.4 MB (big-ws path)
  // overlays (disjoint lifetimes):
  float* nu1fT = ws + 328704;   // over nu2T (k5b2 -> k5c1)
  float* hpart = ws + 721920;   // over W2F/W1F (k5b1 -> k5b2)
  float* ppart = ws + 721920;   // same region (k5c1 -> k5c2)

  const size_t WS_NEED_BIG = (size_t)(1647616 + 32 * 401408) * 4;  // ~58 MB
  bool big = ws_size >= WS_NEED_BIG;

  k_pre<<<1144, 256, 0, stream>>>(x, W1, b1, W2, W1F, W2F, d1B, t1B, dnB, E);
  if (big) {
    k_scaleA<<<dim3(392, 32), 256, 0, stream>>>(W1F, d1B, W1S);
    k3_s<<<dim3(224, 8), 256, 0, stream>>>(W1S, W2F, E);
  } else {
    k3_fb<<<dim3(7, 8, 32), 256, 0, stream>>>(W1F, W2F, d1B, E);
  }
  k245a<<<H2, 256, 0, stream>>>(W2, b2, dnB, t1B, E, W3, y, nu2T, F2);
  k5b1<<<dim3(8, B, 2), 128, 0, stream>>>(W2, nu2T, hpart);
  k5b2<<<dim3(4, B), 256, 0, stream>>>(hpart, d1B, t1B, dnB, nu1fT, F);
  k5c1<<<dim3(7, B, 2), 128, 0, stream>>>(W1, nu1fT, ppart);
  k5c2_out<<<B, 256, 0, stream>>>(ppart, F, F2, b3, y, out);
}

// Round 8
// 225.100 us; speedup vs baseline: 1.5507x; 1.5507x over previous
//
#include <hip/hip_runtime.h>
#include <math.h>

#define B    32
#define INF  784
#define H1   1024
#define H2   1024
#define NC   10
#define EPSV 0.1f

typedef __attribute__((ext_vector_type(8))) short short8;
typedef __attribute__((ext_vector_type(4))) float floatx4;

__device__ inline ushort bf16_rne(float f) {
  uint u = __builtin_bit_cast(uint, f);
  u += 0x7FFFu + ((u >> 16) & 1u);
  return (ushort)(u >> 16);
}
__device__ inline uint pack2(float a, float b) {
  return (uint)bf16_rne(a) | ((uint)bf16_rne(b) << 16);
}
// scale a packed pair of bf16 (in dword u) by d0,d1 and repack (RNE — must
// match r4 numerics: absmax was 3e-13 vs the bf16-ified np reference)
__device__ inline uint scale_pack(uint u, float d0, float d1v) {
  float f0 = __builtin_bit_cast(float, u << 16) * d0;
  float f1 = __builtin_bit_cast(float, u & 0xFFFF0000u) * d1v;
  uint r0 = __builtin_bit_cast(uint, f0) + 0x8000u;
  uint r1 = __builtin_bit_cast(uint, f1) + 0x8000u;
  return __builtin_amdgcn_perm(r1, r0, 0x07060302u);
}

// ---------------------------------------------------------------------------
// K_PRE: merged preprocessing + zero-init.
//  [0,64):     W2F fragment pack
//  [64,113):   W1F fragment pack via LDS transpose (coalesced reads)
//  [113,1137): layer-1 row i = bid-113
//  [1137,1144): zero E/F/F2 region (54272 floats from E base)
// ---------------------------------------------------------------------------
__global__ __launch_bounds__(256) void k_pre(
    const float* __restrict__ x, const float* __restrict__ W1,
    const float* __restrict__ b1, const float* __restrict__ W2,
    ushort* __restrict__ W1F, ushort* __restrict__ W2F,
    float* __restrict__ d1B, float* __restrict__ t1B, float* __restrict__ dnB,
    float* __restrict__ Ezero)
{
  __shared__ float red[4][B + 1];
  __shared__ float Ts[4][32][17];
  int bid = blockIdx.x;
  int t = threadIdx.x;
  if (bid < 64) {
    int jt = bid;
    int lane = t & 63, c0 = t >> 6;
    int l15 = lane & 15, quad = lane >> 4;
    for (int c = c0; c < 32; c += 4) {
      const float* src = &W2[(size_t)(jt * 16 + l15) * H1 + c * 32 + quad * 8];
      float4 v0 = *reinterpret_cast<const float4*>(src);
      float4 v1 = *reinterpret_cast<const float4*>(src + 4);
      uint4 o;
      o.x = pack2(v0.x, v0.y); o.y = pack2(v0.z, v0.w);
      o.z = pack2(v1.x, v1.y); o.w = pack2(v1.z, v1.w);
      *reinterpret_cast<uint4*>(&W2F[((size_t)(c * 64 + jt) * 64 + lane) * 8]) = o;
    }
  } else if (bid < 113) {
    int mt = bid - 64;
    int col0 = mt * 16;
    int w = t >> 6, lane = t & 63;
    int l15 = lane & 15, quad = lane >> 4;
    for (int cg = 0; cg < 8; cg++) {
      int c = cg * 4 + w;
#pragma unroll
      for (int p = 0; p < 8; p++) {
        int r = p * 4 + (lane >> 4);
        Ts[w][r][lane & 15] = W1[(size_t)(c * 32 + r) * INF + col0 + (lane & 15)];
      }
      float f[8];
#pragma unroll
      for (int e = 0; e < 8; e++) f[e] = Ts[w][quad * 8 + e][l15];
      uint4 o;
      o.x = pack2(f[0], f[1]); o.y = pack2(f[2], f[3]);
      o.z = pack2(f[4], f[5]); o.w = pack2(f[6], f[7]);
      *reinterpret_cast<uint4*>(&W1F[((size_t)(c * 49 + mt) * 64 + lane) * 8]) = o;
    }
  } else if (bid < 1137) {
    int i = bid - 113;
    const float* w = W1 + (size_t)i * INF;
    float acc[B];
#pragma unroll
    for (int b = 0; b < B; b++) acc[b] = 0.f;
    float wabs = 0.f;
    for (int k = t; k < INF; k += 256) {
      float wv = w[k];
      wabs += fabsf(wv);
#pragma unroll
      for (int b = 0; b < B; b++) acc[b] = fmaf(x[b * INF + k], wv, acc[b]);
    }
#pragma unroll
    for (int off = 32; off > 0; off >>= 1) {
#pragma unroll
      for (int b = 0; b < B; b++) acc[b] += __shfl_down(acc[b], off, 64);
      wabs += __shfl_down(wabs, off, 64);
    }
    int wave = t >> 6, lane = t & 63;
    if (lane == 0) {
#pragma unroll
      for (int b = 0; b < B; b++) red[wave][b] = acc[b];
      red[wave][B] = wabs;
    }
    __syncthreads();
    if (t < B) {
      float s = red[0][t] + red[1][t] + red[2][t] + red[3][t];
      float r = EPSV * (red[0][B] + red[1][B] + red[2][B] + red[3][B]);
      float nom = s + b1[i];
      float zl = nom - r, zu = nom + r;
      float d, l;
      if (zl >= 0.f)      { d = 1.f;            l = 0.f; }
      else if (zu > 0.f)  { d = zu / (zu - zl); l = zl;  }
      else                { d = 0.f;            l = 0.f; }
      d1B[(size_t)t * H1 + i] = d;
      t1B[(size_t)t * H1 + i] = d * l;
      dnB[(size_t)t * H1 + i] = d * nom;
    }
  } else {
    int zb = bid - 1137;
    for (int idx = t; idx < 8192; idx += 256) {
      int pos = zb * 8192 + idx;
      if (pos < 54272) Ezero[pos] = 0.f;
    }
  }
}

// ---------------------------------------------------------------------------
// K3: E[j,b] = eps * sum_k | sum_i W1[i,k] * (W2[j,i]*d1[b,i]) |
// In-loop d1 scaling (L2-resident working set, FETCH ~14 MB — r4 structure).
// Per wave 7 mt x 2 nt; block 4 waves = 64 j.  grid (7, 8, 32).
// launch_bounds(256,3): 132 unified regs fits 170 -> 3 blocks/CU.
// ---------------------------------------------------------------------------
#define K3_LOAD(c, A, Bv) do {                                                  \
  _Pragma("unroll")                                                             \
  for (int ni = 0; ni < 2; ni++)                                                \
    Bv[ni] = *reinterpret_cast<const uint4*>(bBase + (size_t)(c) * 32768 + ni * 512); \
  _Pragma("unroll")                                                             \
  for (int mi = 0; mi < 7; mi++)                                                \
    A[mi] = *reinterpret_cast<const uint4*>(aBase + (size_t)(c) * 25088 + mi * 512); \
} while (0)

#define K3F_COMP(c, A, Bv) do {                                                 \
  float4 dv0 = *reinterpret_cast<const float4*>(&Ds[(c) * 32 + quad * 8]);      \
  float4 dv1 = *reinterpret_cast<const float4*>(&Ds[(c) * 32 + quad * 8 + 4]);  \
  short8 bfr[2];                                                                \
  _Pragma("unroll")                                                             \
  for (int ni = 0; ni < 2; ni++) {                                              \
    uint4 sb;                                                                   \
    sb.x = scale_pack(Bv[ni].x, dv0.x, dv0.y);                                  \
    sb.y = scale_pack(Bv[ni].y, dv0.z, dv0.w);                                  \
    sb.z = scale_pack(Bv[ni].z, dv1.x, dv1.y);                                  \
    sb.w = scale_pack(Bv[ni].w, dv1.z, dv1.w);                                  \
    bfr[ni] = __builtin_bit_cast(short8, sb);                                   \
  }                                                                             \
  _Pragma("unroll")                                                             \
  for (int mi = 0; mi < 7; mi++) {                                              \
    short8 af = __builtin_bit_cast(short8, A[mi]);                              \
    _Pragma("unroll")                                                           \
    for (int ni = 0; ni < 2; ni++)                                              \
      acc[mi][ni] = __builtin_amdgcn_mfma_f32_16x16x32_bf16(af, bfr[ni], acc[mi][ni], 0, 0, 0); \
  }                                                                             \
} while (0)

__global__ __launch_bounds__(256, 3) void k3(
    const ushort* __restrict__ W1F, const ushort* __restrict__ W2F,
    const float* __restrict__ d1B, float* __restrict__ E)
{
  int b = blockIdx.z;
  int t = threadIdx.x, w = t >> 6, lane = t & 63;
  int quad = lane >> 4, l15 = lane & 15;
  int mt0 = blockIdx.x * 7;
  int jt0 = blockIdx.y * 8 + w * 2;

  __shared__ float Ds[H1];
  for (int idx = t; idx < H1; idx += 256) Ds[idx] = d1B[(size_t)b * H1 + idx];
  __syncthreads();

  const ushort* aBase = W1F + ((size_t)mt0 * 64 + lane) * 8;
  const ushort* bBase = W2F + ((size_t)jt0 * 64 + lane) * 8;

  floatx4 acc[7][2];
#pragma unroll
  for (int mi = 0; mi < 7; mi++)
#pragma unroll
    for (int ni = 0; ni < 2; ni++) acc[mi][ni] = (floatx4){0.f, 0.f, 0.f, 0.f};

  uint4 a0[7], b0[2], a1[7], b1v[2];
  K3_LOAD(0, a0, b0);
  K3_LOAD(1, a1, b1v);
  for (int c = 0; c < 30; c += 2) {
    K3F_COMP(c, a0, b0);
    K3_LOAD(c + 2, a0, b0);
    K3F_COMP(c + 1, a1, b1v);
    if (c + 3 < 32) K3_LOAD(c + 3, a1, b1v);
  }
  K3F_COMP(30, a0, b0);
  K3F_COMP(31, a1, b1v);

#pragma unroll
  for (int ni = 0; ni < 2; ni++) {
    float s = 0.f;
#pragma unroll
    for (int mi = 0; mi < 7; mi++)
#pragma unroll
      for (int r = 0; r < 4; r++) s += fabsf(acc[mi][ni][r]);
    s += __shfl_xor(s, 16, 64);
    s += __shfl_xor(s, 32, 64);
    if (lane < 16) {
      int j = (jt0 + ni) * 16 + l15;
      atomicAdd(&E[(size_t)j * B + b], EPSV * s);
    }
  }
}

// ---------------------------------------------------------------------------
// K245A: fused k2 matvecs + combine + nu2 build.  One block per j (= i2).
//  NOTE: B*NC = 320 > 256 threads -> phase2 is a strided loop.
// ---------------------------------------------------------------------------
__global__ __launch_bounds__(256) void k245a(
    const float* __restrict__ W2, const float* __restrict__ b2,
    const float* __restrict__ dnB, const float* __restrict__ t1B,
    const float* __restrict__ E, const float* __restrict__ W3,
    const int* __restrict__ y,
    float* __restrict__ nu2T, float* __restrict__ F2)
{
  int j = blockIdx.x;
  int t = threadIdx.x;
  int wave = t >> 6, lane = t & 63;
  int b0 = wave * 8;
  float aA[8] = {}, aCl[8] = {}, aCu[8] = {};
  const float* __restrict__ w2 = W2 + (size_t)j * H1;
  for (int i = lane; i < H1; i += 64) {
    float wv = w2[i];
    float wp = fmaxf(wv, 0.f), wn = fmaxf(-wv, 0.f);
#pragma unroll
    for (int r = 0; r < 8; r++) {
      float dv = dnB[(size_t)(b0 + r) * H1 + i];
      float tv = t1B[(size_t)(b0 + r) * H1 + i];
      aA[r]  = fmaf(wv, dv, aA[r]);
      aCl[r] = fmaf(wn, tv, aCl[r]);
      aCu[r] = fmaf(wp, tv, aCu[r]);
    }
  }
#pragma unroll
  for (int off = 32; off > 0; off >>= 1) {
#pragma unroll
    for (int r = 0; r < 8; r++) {
      aA[r]  += __shfl_down(aA[r],  off, 64);
      aCl[r] += __shfl_down(aCl[r], off, 64);
      aCu[r] += __shfl_down(aCu[r], off, 64);
    }
  }
  __shared__ float sA[B], sCl[B], sCu[B];
  __shared__ float sd2[B], st2[B], sdb[B], swy[B], sw3[NC];
  float bj = b2[j];
  if (lane == 0) {
#pragma unroll
    for (int r = 0; r < 8; r++) {
      sA [b0 + r] = aA[r] + bj;
      sCl[b0 + r] = aCl[r];
      sCu[b0 + r] = aCu[r];
    }
  }
  if (t >= 64 && t < 96)   swy[t - 64]  = W3[(size_t)y[t - 64] * H2 + j];
  if (t >= 128 && t < 138) sw3[t - 128] = W3[(size_t)(t - 128) * H2 + j];
  __syncthreads();
  if (t < B) {
    float a = sA[t], e = E[(size_t)j * B + t];
    float zl = a - e + sCl[t];
    float zu = a + e - sCu[t];
    float d, l;
    if (zl >= 0.f)      { d = 1.f;            l = 0.f; }
    else if (zu > 0.f)  { d = zu / (zu - zl); l = zl;  }
    else                { d = 0.f;            l = 0.f; }
    sd2[t] = d;
    st2[t] = d * l;
    sdb[t] = d * bj;
  }
  __syncthreads();
  for (int tt = t; tt < B * NC; tt += 256) {   // B*NC=320 > 256: strided!
    int b = tt / NC, jc = tt - b * NC;
    float cw = swy[b] - sw3[jc];
    float d2v = sd2[b];
    nu2T[((size_t)b * H2 + j) * 12 + jc] = cw * d2v;
    float val = cw * sdb[b] + fmaxf(-cw, 0.f) * st2[b];
    atomicAdd(&F2[((size_t)(j & 63) * B + b) * NC + jc], val);
  }
}

// ---------------------------------------------------------------------------
// K5b1: hpart[s][b][j][i1] = sum_{i2 in slice s (128)} nu2T[b][i2][j]*W2[i2,i1]
// 8 slices for parallelism; float2 i1 per thread.  grid (2, 32, 8), block 256.
// ---------------------------------------------------------------------------
__global__ __launch_bounds__(256) void k5b1(
    const float* __restrict__ W2, const float* __restrict__ nu2T,
    float* __restrict__ hpart)
{
  int t = threadIdx.x;
  int i1 = blockIdx.x * 512 + t * 2;
  int b = blockIdx.y, s = blockIdx.z;
  const float* __restrict__ nrowb = nu2T + ((size_t)b * H2 + s * 128) * 12;
  const float* __restrict__ w2b = W2 + (size_t)s * 128 * H1 + i1;
  float h0[NC] = {}, h1[NC] = {};
  for (int i2 = 0; i2 < 128; i2++) {
    float2 wv = *reinterpret_cast<const float2*>(&w2b[(size_t)i2 * H1]);
    const float* __restrict__ nrow = nrowb + i2 * 12;
#pragma unroll
    for (int j = 0; j < NC; j++) {
      h0[j] = fmaf(nrow[j], wv.x, h0[j]);
      h1[j] = fmaf(nrow[j], wv.y, h1[j]);
    }
  }
#pragma unroll
  for (int j = 0; j < NC; j++) {
    float2 o; o.x = h0[j]; o.y = h1[j];
    *reinterpret_cast<float2*>(&hpart[(((size_t)s * B + b) * NC + j) * H1 + i1]) = o;
  }
}

// ---------------------------------------------------------------------------
// K5b2: h = sum_s hpart; nu1fT[b][i1][j] = h*d1; F += h*dn + relu(-h)*t1m
// ---------------------------------------------------------------------------
__global__ __launch_bounds__(256) void k5b2(
    const float* __restrict__ hpart,
    const float* __restrict__ d1B, const float* __restrict__ t1B,
    const float* __restrict__ dnB,
    float* __restrict__ nu1fT, float* __restrict__ F)
{
  int t = threadIdx.x;
  int i1 = blockIdx.x * 256 + t;
  int b = blockIdx.y;
  float d1v = d1B[(size_t)b * H1 + i1];
  float t1v = t1B[(size_t)b * H1 + i1];
  float dnv = dnB[(size_t)b * H1 + i1];
  float sn[NC], c1[NC];
#pragma unroll
  for (int j = 0; j < NC; j++) {
    float hv = 0.f;
#pragma unroll
    for (int s = 0; s < 8; s++)
      hv += hpart[(((size_t)s * B + b) * NC + j) * H1 + i1];
    nu1fT[((size_t)b * H1 + i1) * 12 + j] = hv * d1v;
    sn[j] = hv * dnv;
    c1[j] = fmaxf(-hv, 0.f) * t1v;
  }
#pragma unroll
  for (int off = 32; off > 0; off >>= 1) {
#pragma unroll
    for (int j = 0; j < NC; j++) {
      sn[j] += __shfl_down(sn[j], off, 64);
      c1[j] += __shfl_down(c1[j], off, 64);
    }
  }
  __shared__ float red[4][2 * NC];
  int wave = t >> 6, lane = t & 63;
  if (lane == 0) {
#pragma unroll
    for (int j = 0; j < NC; j++) { red[wave][j] = sn[j]; red[wave][NC + j] = c1[j]; }
  }
  __syncthreads();
  if (t < NC) {
    float s = 0.f;
    for (int w = 0; w < 4; w++) s += red[w][t] + red[w][NC + t];
    atomicAdd(&F[b * NC + t], s);
  }
}

// ---------------------------------------------------------------------------
// K5c1: ppart[s][b][j][k] = sum_{i1 in slice s (128)} nu1fT[b][i1][j]*W1[i1,k]
// grid (7, 32, 8), block 128 (t<112 active).
// ---------------------------------------------------------------------------
__global__ __launch_bounds__(128) void k5c1(
    const float* __restrict__ W1, const float* __restrict__ nu1fT,
    float* __restrict__ ppart)
{
  int t = threadIdx.x;
  bool valid = (t < 112);
  int k = blockIdx.x * 112 + (valid ? t : 0);
  int b = blockIdx.y, s = blockIdx.z;
  const float* __restrict__ nrowb = nu1fT + ((size_t)b * H1 + s * 128) * 12;
  const float* __restrict__ w1b = W1 + (size_t)s * 128 * INF + k;
  float acc[NC] = {};
  for (int i1 = 0; i1 < 128; i1++) {
    float w1v = w1b[(size_t)i1 * INF];
    const float* __restrict__ nrow = nrowb + i1 * 12;
#pragma unroll
    for (int j = 0; j < NC; j++) acc[j] = fmaf(nrow[j], w1v, acc[j]);
  }
  if (valid) {
#pragma unroll
    for (int j = 0; j < NC; j++)
      ppart[(((size_t)s * B + b) * NC + j) * INF + k] = acc[j];
  }
}

// ---------------------------------------------------------------------------
// K5c2 + out: per b: Ef[j] = eps*sum_k |sum_s ppart|;
// out = eps*Ef - (F + sum_slots F2 + b3[yb]-b3[jc]).
// ---------------------------------------------------------------------------
__global__ __launch_bounds__(256) void k5c2_out(
    const float* __restrict__ ppart, const float* __restrict__ F,
    const float* __restrict__ F2, const float* __restrict__ b3,
    const int* __restrict__ y, float* __restrict__ out)
{
  int b = blockIdx.x;
  int t = threadIdx.x;
  float e[NC] = {};
  for (int k = t; k < INF; k += 256) {
#pragma unroll
    for (int j = 0; j < NC; j++) {
      float v = 0.f;
#pragma unroll
      for (int s = 0; s < 8; s++)
        v += ppart[(((size_t)s * B + b) * NC + j) * INF + k];
      e[j] += fabsf(v);
    }
  }
#pragma unroll
  for (int off = 32; off > 0; off >>= 1) {
#pragma unroll
    for (int j = 0; j < NC; j++) e[j] += __shfl_down(e[j], off, 64);
  }
  __shared__ float red[4][NC];
  int wave = t >> 6, lane = t & 63;
  if (lane == 0) {
#pragma unroll
    for (int j = 0; j < NC; j++) red[wave][j] = e[j];
  }
  __syncthreads();
  if (t < NC) {
    float ef = 0.f;
    for (int w = 0; w < 4; w++) ef += red[w][t];
    float s = F[b * NC + t];
    for (int slot = 0; slot < 64; slot++)
      s += F2[((size_t)slot * B + b) * NC + t];
    int yb = y[b];
    s += b3[yb] - b3[t];
    out[b * NC + t] = EPSV * ef - s;
  }
}

// ---------------------------------------------------------------------------
extern "C" void kernel_launch(void* const* d_in, const int* in_sizes, int n_in,
                              void* d_out, int out_size, void* d_ws, size_t ws_size,
                              hipStream_t stream) {
  const float* x  = (const float*)d_in[0];
  const int*   y  = (const int*)  d_in[1];
  const float* W1 = (const float*)d_in[2];
  const float* b1 = (const float*)d_in[3];
  const float* W2 = (const float*)d_in[4];
  const float* b2 = (const float*)d_in[5];
  const float* W3 = (const float*)d_in[6];
  const float* b3 = (const float*)d_in[7];
  float* out = (float*)d_out;
  float* ws  = (float*)d_ws;

  // ---- workspace layout (floats), with lifetime overlays ----
  float* d1B  = ws;
  float* t1B  = ws + 32768;
  float* dnB  = ws + 65536;
  float* E    = ws + 196608;    // 32768 (zeroed in k_pre)
  float* F    = ws + 229376;    // 320, pad to 1024 (zeroed)
  float* F2   = ws + 230400;    // 64*32*10 = 20480 (zeroed; zero-range 54272 from E)
  float* nu2T = ws + 328704;    // 393216, k245a -> k5b1 (ends 721920)
  ushort* W2F = (ushort*)(ws + 721920);    // 1048576 us (ends 1246208)
  ushort* W1F = (ushort*)(ws + 1246208);   // 802816 us (ends 1647616)
  // overlays (disjoint lifetimes):
  float* nu1fT = ws + 328704;   // over nu2T (k5b2 -> k5c1)
  float* hpart = ws + 721920;   // 8*32*10*1024 = 2621440 f over W2F/W1F (k5b1 -> k5b2)
  float* ppart = ws + 721920;   // 8*32*10*784 = 2007040 f, same region (k5c1 -> k5c2)

  k_pre<<<1144, 256, 0, stream>>>(x, W1, b1, W2, W1F, W2F, d1B, t1B, dnB, E);
  k3<<<dim3(7, 8, 32), 256, 0, stream>>>(W1F, W2F, d1B, E);
  k245a<<<H2, 256, 0, stream>>>(W2, b2, dnB, t1B, E, W3, y, nu2T, F2);
  k5b1<<<dim3(2, B, 8), 256, 0, stream>>>(W2, nu2T, hpart);
  k5b2<<<dim3(4, B), 256, 0, stream>>>(hpart, d1B, t1B, dnB, nu1fT, F);
  k5c1<<<dim3(7, B, 8), 128, 0, stream>>>(W1, nu1fT, ppart);
  k5c2_out<<<B, 256, 0, stream>>>(ppart, F, F2, b3, y, out);
}